// Round 13
// baseline (16656.937 us; speedup 1.0000x reference)
//
#include <hip/hip_runtime.h>
#include <math.h>

// Point-MAE Group — FPS(2048) + kNN(16) + gather/subtract.
// B=4, N=16384, G=2048, M=16.
// NUMERICS CONTRACT (verified absmax=0.0 rounds 4-12 — do not change):
//  - FPS d: ((dx*dx)+(dy*dy))+(dz*dz), separate f32 ops, no FMA.
//    Packed VOP3P (pk_add/pk_mul) = two independent IEEE f32 ops (proven
//    r11/r12); x + (-p) == x - p exactly.
//  - kNN: d2 = (cc - 2*dot) + xx; ONLY dot is an FMA chain (numpy einsum).
//  - FPS argmax: first occurrence of max; top-16: stable ascending order.
//
// Round-13: r6-r12 proved the full-update iteration is irreducible (~2µs/iter
// across 5 structurally different kernels). This round shrinks the WORK:
// exact spatial pruning. Tile (32 pts, spatially compact via 8^3-cell sort)
// caches max-md key; if dist(p,bbox)^2 >= maxmd*1.001 the whole tile provably
// cannot change (min(md,d)=md for all members, margin covers f32 rounding) ->
// skip. Cached keys keep the argmax exact (value, then lowest ORIGINAL index).
// Main loop = ONE wave, zero barriers: 8 bbox checks/lane, rare clustered
// updates, u64 butterfly, one broadcast float4 for winner coords.
// Scatter order is atomic-nondeterministic but output-invariant (keys order
// by (value, orig idx); skips are no-ops) -> deterministic results.

#pragma clang fp contract(off)

#define N_PTS 16384
#define N_GROUP 2048
#define GROUP_SIZE 16
#define SETUP_THREADS 512
#define NTILE 512
#define NSLOT 8                 // tiles per lane (512/64)
#define NPAIRT 16               // point-pairs per tile
#define NCELL 512
#define KNN_THREADS 256
#define KNN_WAVES (KNN_THREADS / 64)
// ws float layout per batch: [wsx 16384][wsy 16384][wsz 16384][ws4 65536]
#define WS_PER_BATCH (16384 * 3 + 16384 * 4)

// a*b as a standalone instruction (kNN only — keep the exact passing form).
__device__ __forceinline__ float fmul_sep(float a, float b) {
  float r = a * b;
  asm volatile("" : "+v"(r));
  return r;
}

__device__ __forceinline__ unsigned long long shfl_xor_u64(unsigned long long v, int off) {
  const unsigned int lo = __shfl_xor((unsigned int)v, off);
  const unsigned int hi = __shfl_xor((unsigned int)(v >> 32), off);
  return ((unsigned long long)hi << 32) | lo;
}
__device__ __forceinline__ unsigned long long maxu64(unsigned long long a,
                                                     unsigned long long b) {
  return a > b ? a : b;
}
__device__ __forceinline__ float2 pk_add(float2 a, float2 b) {
  float2 d;
  asm("v_pk_add_f32 %0, %1, %2" : "=v"(d) : "v"(a), "v"(b));
  return d;
}
__device__ __forceinline__ float2 pk_sq(float2 a) {
  float2 d;
  asm("v_pk_mul_f32 %0, %1, %1" : "=v"(d) : "v"(a));
  return d;
}

__device__ __forceinline__ int cell_coord(float v, float mn, float s) {
  int c = (int)((v - mn) * s);
  return c < 0 ? 0 : (c > 7 ? 7 : c);
}

// ---------------------------------------------------------------------------
// FPS with exact tile pruning. One block per batch; setup uses 512 threads,
// the 2047-step serial loop runs on wave 0 only (no barriers).
// ---------------------------------------------------------------------------
__global__ __launch_bounds__(SETUP_THREADS) void fps_kernel(
    const float* __restrict__ pcd, float* __restrict__ center,
    float* __restrict__ ws) {
#pragma clang fp contract(off)
  const int b = blockIdx.x;
  const int t = threadIdx.x;
  const int lane = t & 63;
  const int wid = t >> 6;
  const float* xyz = pcd + (size_t)b * N_PTS * 3;
  float* wsx = ws + (size_t)b * WS_PER_BATCH;
  float* wsy = wsx + 16384;
  float* wsz = wsy + 16384;
  float* ws4 = wsz + 16384;

  __shared__ float2 md2[NPAIRT * NTILE];    // 64 KiB, [k*512 + tile]
  __shared__ unsigned short oidx16[N_PTS];  // 32 KiB, [(k*512+tile)*2+comp]
  __shared__ int hist[NCELL], base_[NCELL], cnt[NCELL];
  __shared__ int scanA[NCELL], scanB[NCELL];
  __shared__ float bb6[6];                  // minx,miny,minz, sx,sy,sz
  __shared__ float wred[8][6];

  // ---- setup: batch bbox ----
  hist[t] = 0; cnt[t] = 0;
  float mnx = 1e30f, mny = 1e30f, mnz = 1e30f;
  float mxx = -1e30f, mxy = -1e30f, mxz = -1e30f;
  for (int i = 0; i < 32; ++i) {
    const int idx = t * 32 + i;
    const float x = xyz[idx * 3 + 0];
    const float y = xyz[idx * 3 + 1];
    const float z = xyz[idx * 3 + 2];
    mnx = fminf(mnx, x); mxx = fmaxf(mxx, x);
    mny = fminf(mny, y); mxy = fmaxf(mxy, y);
    mnz = fminf(mnz, z); mxz = fmaxf(mxz, z);
  }
#pragma unroll
  for (int off = 32; off > 0; off >>= 1) {
    mnx = fminf(mnx, __shfl_xor(mnx, off)); mxx = fmaxf(mxx, __shfl_xor(mxx, off));
    mny = fminf(mny, __shfl_xor(mny, off)); mxy = fmaxf(mxy, __shfl_xor(mxy, off));
    mnz = fminf(mnz, __shfl_xor(mnz, off)); mxz = fmaxf(mxz, __shfl_xor(mxz, off));
  }
  if (lane == 0) {
    wred[wid][0] = mnx; wred[wid][1] = mny; wred[wid][2] = mnz;
    wred[wid][3] = mxx; wred[wid][4] = mxy; wred[wid][5] = mxz;
  }
  __syncthreads();
  if (t == 0) {
    float a0 = wred[0][0], a1 = wred[0][1], a2 = wred[0][2];
    float a3 = wred[0][3], a4 = wred[0][4], a5 = wred[0][5];
    for (int j = 1; j < 8; ++j) {
      a0 = fminf(a0, wred[j][0]); a1 = fminf(a1, wred[j][1]);
      a2 = fminf(a2, wred[j][2]); a3 = fmaxf(a3, wred[j][3]);
      a4 = fmaxf(a4, wred[j][4]); a5 = fmaxf(a5, wred[j][5]);
    }
    bb6[0] = a0; bb6[1] = a1; bb6[2] = a2;
    bb6[3] = 8.0f / fmaxf(a3 - a0, 1e-30f);
    bb6[4] = 8.0f / fmaxf(a4 - a1, 1e-30f);
    bb6[5] = 8.0f / fmaxf(a5 - a2, 1e-30f);
  }
  __syncthreads();
  const float c_mnx = bb6[0], c_mny = bb6[1], c_mnz = bb6[2];
  const float c_sx = bb6[3], c_sy = bb6[4], c_sz = bb6[5];

  // ---- setup: histogram ----
  for (int i = 0; i < 32; ++i) {
    const int idx = t * 32 + i;
    const int cx = cell_coord(xyz[idx * 3 + 0], c_mnx, c_sx);
    const int cy = cell_coord(xyz[idx * 3 + 1], c_mny, c_sy);
    const int cz = cell_coord(xyz[idx * 3 + 2], c_mnz, c_sz);
    atomicAdd(&hist[(cx << 6) | (cy << 3) | cz], 1);
  }
  __syncthreads();
  // ---- setup: inclusive scan (Hillis-Steele ping-pong) ----
  scanA[t] = hist[t];
  __syncthreads();
#pragma unroll
  for (int step = 0; step < 9; ++step) {
    const int off = 1 << step;
    int* src = (step & 1) ? scanB : scanA;
    int* dst = (step & 1) ? scanA : scanB;
    const int v = src[t] + (t >= off ? src[t - off] : 0);
    dst[t] = v;
    __syncthreads();
  }
  base_[t] = scanB[t] - hist[t];  // step 8 wrote scanB (last dst when step even)
  __syncthreads();
  // ---- setup: scatter into ws + oidx; init md ----
  for (int i = 0; i < 32; ++i) {
    const int idx = t * 32 + i;
    const float x = xyz[idx * 3 + 0];
    const float y = xyz[idx * 3 + 1];
    const float z = xyz[idx * 3 + 2];
    const int cx = cell_coord(x, c_mnx, c_sx);
    const int cy = cell_coord(y, c_mny, c_sy);
    const int cz = cell_coord(z, c_mnz, c_sz);
    const int c = (cx << 6) | (cy << 3) | cz;
    const int pos = base_[c] + atomicAdd(&cnt[c], 1);
    const int tile = pos >> 5, w = pos & 31, k = w >> 1, comp = w & 1;
    wsx[(k * NTILE + tile) * 2 + comp] = x;
    wsy[(k * NTILE + tile) * 2 + comp] = y;
    wsz[(k * NTILE + tile) * 2 + comp] = z;
    ws4[pos * 4 + 0] = x; ws4[pos * 4 + 1] = y; ws4[pos * 4 + 2] = z;
    oidx16[(k * NTILE + tile) * 2 + comp] = (unsigned short)idx;
  }
#pragma unroll
  for (int j = 0; j < NPAIRT; ++j) md2[j * NTILE + t] = make_float2(1e10f, 1e10f);
  __threadfence_block();
  __syncthreads();
  if (wid != 0) return;  // waves 1..7 done; wave 0 runs the serial loop

  // ---- wave 0: tile bboxes + initial keys ----
  const float2* wx2 = (const float2*)wsx;
  const float2* wy2 = (const float2*)wsy;
  const float2* wz2 = (const float2*)wsz;
  const unsigned* op32 = (const unsigned*)oidx16;
  const unsigned long long V1E10 = (unsigned long long)__float_as_uint(1e10f) << 32;

  float bxl[NSLOT], bxh[NSLOT], byl[NSLOT], byh[NSLOT], bzl[NSLOT], bzh[NSLOT];
  unsigned long long tkey[NSLOT];
#pragma unroll
  for (int s = 0; s < NSLOT; ++s) {
    const int tile = s * 64 + lane;
    float l0 = 1e30f, l1 = 1e30f, l2 = 1e30f, h0 = -1e30f, h1 = -1e30f, h2 = -1e30f;
    unsigned long long nk = 0;
    for (int k = 0; k < NPAIRT; ++k) {
      const float2 X = wx2[k * NTILE + tile];
      const float2 Y = wy2[k * NTILE + tile];
      const float2 Z = wz2[k * NTILE + tile];
      l0 = fminf(l0, fminf(X.x, X.y)); h0 = fmaxf(h0, fmaxf(X.x, X.y));
      l1 = fminf(l1, fminf(Y.x, Y.y)); h1 = fmaxf(h1, fmaxf(Y.x, Y.y));
      l2 = fminf(l2, fminf(Z.x, Z.y)); h2 = fmaxf(h2, fmaxf(Z.x, Z.y));
      const unsigned op = op32[k * NTILE + tile];
      const unsigned long long k0 =
          V1E10 | ((unsigned long long)((16383u - (op & 0xffffu)) << 14)) |
          (unsigned)(tile * 32 + 2 * k);
      const unsigned long long k1 =
          V1E10 | ((unsigned long long)((16383u - (op >> 16)) << 14)) |
          (unsigned)(tile * 32 + 2 * k + 1);
      nk = maxu64(nk, maxu64(k0, k1));
    }
    bxl[s] = l0; bxh[s] = h0; byl[s] = l1; byh[s] = h1; bzl[s] = l2; bzh[s] = h2;
    tkey[s] = nk;
    asm("" : "+v"(bxl[s]), "+v"(bxh[s]), "+v"(byl[s]), "+v"(byh[s]),
              "+v"(bzl[s]), "+v"(bzh[s]));  // keep bbox register-resident
  }

  float px = xyz[0], py = xyz[1], pz = xyz[2];
  if (lane == 0) {
    center[((size_t)b * N_GROUP) * 3 + 0] = px;
    center[((size_t)b * N_GROUP) * 3 + 1] = py;
    center[((size_t)b * N_GROUP) * 3 + 2] = pz;
  }
  const float4* w4 = (const float4*)ws4;

  // ---- serial FPS loop: no barriers ----
  for (int it = 1; it < N_GROUP; ++it) {
    const float2 npx2 = make_float2(-px, -px);
    const float2 npy2 = make_float2(-py, -py);
    const float2 npz2 = make_float2(-pz, -pz);
#pragma unroll
    for (int s = 0; s < NSLOT; ++s) {
      const int tile = s * 64 + lane;
      const float U = __uint_as_float((unsigned)(tkey[s] >> 32));
      const float ddx = fmaxf(fmaxf(bxl[s] - px, px - bxh[s]), 0.0f);
      const float ddy = fmaxf(fmaxf(byl[s] - py, py - byh[s]), 0.0f);
      const float ddz = fmaxf(fmaxf(bzl[s] - pz, pz - bzh[s]), 0.0f);
      const float pd = ((ddx * ddx) + (ddy * ddy)) + (ddz * ddz);
      // conservative skip: margin 1.001 >> accumulated f32 rounding
      const bool act = pd < U * 1.001f;
      if (__ballot(act)) {
        if (act) {
          unsigned long long nk = 0;
#pragma unroll 4
          for (int k = 0; k < NPAIRT; ++k) {
            const float2 X = wx2[k * NTILE + tile];
            const float2 Y = wy2[k * NTILE + tile];
            const float2 Z = wz2[k * NTILE + tile];
            float2 M = md2[k * NTILE + tile];
            const float2 dX = pk_add(X, npx2);   // x + (-px) == x - px
            const float2 dY = pk_add(Y, npy2);
            const float2 dZ = pk_add(Z, npz2);
            const float2 s2 = pk_add(pk_add(pk_sq(dX), pk_sq(dY)), pk_sq(dZ));
            M.x = fminf(M.x, s2.x);
            M.y = fminf(M.y, s2.y);
            md2[k * NTILE + tile] = M;
            const unsigned op = op32[k * NTILE + tile];
            const unsigned long long k0 =
                ((unsigned long long)__float_as_uint(M.x) << 32) |
                ((unsigned long long)((16383u - (op & 0xffffu)) << 14)) |
                (unsigned)(tile * 32 + 2 * k);
            const unsigned long long k1 =
                ((unsigned long long)__float_as_uint(M.y) << 32) |
                ((unsigned long long)((16383u - (op >> 16)) << 14)) |
                (unsigned)(tile * 32 + 2 * k + 1);
            nk = maxu64(nk, maxu64(k0, k1));
          }
          tkey[s] = nk;
        }
      }
    }
    // lane tree over 8 slots, then wave butterfly (max key).
    unsigned long long w01 = maxu64(tkey[0], tkey[1]);
    unsigned long long w23 = maxu64(tkey[2], tkey[3]);
    unsigned long long w45 = maxu64(tkey[4], tkey[5]);
    unsigned long long w67 = maxu64(tkey[6], tkey[7]);
    unsigned long long w = maxu64(maxu64(w01, w23), maxu64(w45, w67));
#pragma unroll
    for (int off = 32; off > 0; off >>= 1) w = maxu64(w, shfl_xor_u64(w, off));
    const int pos = (int)(w & 0x3fffull);
    const float4 pw = w4[pos];  // broadcast read: winner coords (bit-copies)
    px = pw.x; py = pw.y; pz = pw.z;
    if (lane == 0) {
      center[((size_t)b * N_GROUP + it) * 3 + 0] = px;
      center[((size_t)b * N_GROUP + it) * 3 + 1] = py;
      center[((size_t)b * N_GROUP + it) * 3 + 2] = pz;
    }
  }
}

// ---------------------------------------------------------------------------
// kNN: one wave per center; lanes 0..15 hold the sorted top-16.
// d2 = (cc - 2*dot) + xx; cc/xx separate ops; dot = FMA chain (einsum).
// (unchanged from the bit-exact round-4 version)
// ---------------------------------------------------------------------------
__global__ __launch_bounds__(KNN_THREADS) void knn_kernel(
    const float* __restrict__ pcd, const float* __restrict__ center,
    float* __restrict__ nbr) {
#pragma clang fp contract(off)
  const int lane = threadIdx.x & 63;
  const int gw = blockIdx.x * KNN_WAVES + (threadIdx.x >> 6);  // center id
  const int b = gw >> 11;                                      // G = 2048
  const float* xyz = pcd + (size_t)b * N_PTS * 3;

  const float c0 = center[(size_t)gw * 3 + 0];
  const float c1 = center[(size_t)gw * 3 + 1];
  const float c2 = center[(size_t)gw * 3 + 2];
  const float cc = (fmul_sep(c0, c0) + fmul_sep(c1, c1)) + fmul_sep(c2, c2);

  float lval = INFINITY;  // lanes 0..15: sorted list values (ascending)
  int lidx = 0;
  float worst = INFINITY; // 16th-smallest so far, wave-uniform

  for (int ch = 0; ch < N_PTS / 64; ++ch) {
    const int n = ch * 64 + lane;
    const float xp = xyz[n * 3 + 0];
    const float yp = xyz[n * 3 + 1];
    const float zp = xyz[n * 3 + 2];
    const float xx = (fmul_sep(xp, xp) + fmul_sep(yp, yp)) + fmul_sep(zp, zp);
    // numpy einsum: acc=0; acc=fma(c0,x,acc); acc=fma(c1,y,acc); acc=fma(c2,z,acc)
    const float dot = fmaf(c2, zp, fmaf(c1, yp, c0 * xp));
    const float d2 = (cc - fmul_sep(2.0f, dot)) + xx;

    unsigned long long m = __ballot(d2 < worst);
    while (m) {
      const int srcl = __ffsll((unsigned long long)m) - 1;  // ascending index
      m &= (m - 1);
      const float nv = __shfl(d2, srcl);
      if (nv < worst) {  // wave-uniform decision
        const int ni = ch * 64 + srcl;
        const int rank = __popcll(__ballot(lane < GROUP_SIZE && lval <= nv));
        const float shv = __shfl_up(lval, 1);
        const int   shi = __shfl_up(lidx, 1);
        if (lane < GROUP_SIZE) {
          if (lane == rank)      { lval = nv;  lidx = ni;  }
          else if (lane > rank)  { lval = shv; lidx = shi; }
        }
        worst = __shfl(lval, 15);
      }
    }
  }

  if (lane < GROUP_SIZE) {
    const float ox = xyz[lidx * 3 + 0] - c0;
    const float oy = xyz[lidx * 3 + 1] - c1;
    const float oz = xyz[lidx * 3 + 2] - c2;
    const size_t o = ((size_t)gw * GROUP_SIZE + lane) * 3;
    nbr[o + 0] = ox; nbr[o + 1] = oy; nbr[o + 2] = oz;
  }
}

extern "C" void kernel_launch(void* const* d_in, const int* in_sizes, int n_in,
                              void* d_out, int out_size, void* d_ws, size_t ws_size,
                              hipStream_t stream) {
  const float* pcd = (const float*)d_in[0];
  const int B = in_sizes[0] / (N_PTS * 3);  // = 4

  float* out = (float*)d_out;
  float* nbr = out;                                            // B*G*M*3
  float* center = out + (size_t)B * N_GROUP * GROUP_SIZE * 3;  // B*G*3

  fps_kernel<<<B, SETUP_THREADS, 0, stream>>>(pcd, center, (float*)d_ws);
  knn_kernel<<<(B * N_GROUP) / KNN_WAVES, KNN_THREADS, 0, stream>>>(pcd, center, nbr);
}

// Round 14
// 6423.421 us; speedup vs baseline: 2.5932x; 2.5932x over previous
//
#include <hip/hip_runtime.h>
#include <math.h>

// Point-MAE Group — FPS(2048) + kNN(16) + gather/subtract.
// B=4, N=16384, G=2048, M=16.
// NUMERICS CONTRACT (verified absmax=0.0 rounds 4-13 — do not change):
//  - FPS d: ((dx*dx)+(dy*dy))+(dz*dz), separate f32 ops, no FMA.
//    Packed VOP3P pk_add/pk_mul = two independent IEEE f32 ops (r11-13);
//    x + (-p) == x - p exactly.
//  - kNN: d2 = (cc - 2*dot) + xx; ONLY dot is an FMA chain (numpy einsum).
//  - FPS argmax: first occurrence of max (ties -> lowest ORIGINAL index);
//    top-16: stable ascending.
//
// Round-14: r13 proved exact tile pruning (absmax 0.0) but ran it on ONE
// wave with global latency exposed (8-27µs/iter). This round mounts the same
// pruning on the proven 8-wave chassis (r6 tail, 1 barrier/iter):
//  - 512 threads; thread t owns tile t = 32 spatially-sorted points.
//  - per-iter: register bbox test vs cached tile key U (skip margin 1.001 —
//    conservative vs all f32 rounding, r13-proven); active threads update
//    md (LDS) from global sorted SoA (pair-transposed) and rebuild the key
//    from register-packed inv-orig (OP[16]).
//  - keys: (md_bits<<32)|(inv_orig<<14)|pos — u64 order == (value, lowest
//    orig). Atomic scatter order is output-invariant (inv unique per point).
//  - tail: u64 wave butterfly -> lane0 prefetches winner coords under the
//    barrier -> 8-key scan (r6's proven fastest tail).

#pragma clang fp contract(off)

#define N_PTS 16384
#define N_GROUP 2048
#define GROUP_SIZE 16
#define FPS_THREADS 512
#define NTILE 512
#define NPAIRT 16               // point-pairs per tile (32 pts)
#define NCELL 512
#define KNN_THREADS 256
#define KNN_WAVES (KNN_THREADS / 64)
#define WS_PER_BATCH (3 * 16384)   // wsx | wsy | wsz (pair-transposed float2)

// a*b as a standalone instruction (kNN only — keep the exact passing form).
__device__ __forceinline__ float fmul_sep(float a, float b) {
  float r = a * b;
  asm volatile("" : "+v"(r));
  return r;
}

__device__ __forceinline__ unsigned long long shfl_xor_u64(unsigned long long v, int off) {
  const unsigned int lo = __shfl_xor((unsigned int)v, off);
  const unsigned int hi = __shfl_xor((unsigned int)(v >> 32), off);
  return ((unsigned long long)hi << 32) | lo;
}
__device__ __forceinline__ unsigned long long maxu64(unsigned long long a,
                                                     unsigned long long b) {
  return a > b ? a : b;
}
__device__ __forceinline__ float2 pk_add(float2 a, float2 b) {
  float2 d;
  asm("v_pk_add_f32 %0, %1, %2" : "=v"(d) : "v"(a), "v"(b));
  return d;
}
__device__ __forceinline__ float2 pk_sq(float2 a) {
  float2 d;
  asm("v_pk_mul_f32 %0, %1, %1" : "=v"(d) : "v"(a));
  return d;
}
__device__ __forceinline__ int cell_coord(float v, float mn, float s) {
  int c = (int)((v - mn) * s);
  return c < 0 ? 0 : (c > 7 ? 7 : c);
}

// ---------------------------------------------------------------------------
// FPS with exact tile pruning, 8 waves, 1 barrier/iter.
// ---------------------------------------------------------------------------
__global__ __launch_bounds__(FPS_THREADS)
__attribute__((amdgpu_waves_per_eu(2, 2)))
void fps_kernel(const float* __restrict__ pcd, float* __restrict__ center,
                float* __restrict__ ws) {
#pragma clang fp contract(off)
  const int b = blockIdx.x;
  const int t = threadIdx.x;
  const int lane = t & 63;
  const int wid = t >> 6;
  const float* xyz = pcd + (size_t)b * N_PTS * 3;
  float* wsx = ws + (size_t)b * WS_PER_BATCH;
  float* wsy = wsx + N_PTS;
  float* wsz = wsy + N_PTS;

  __shared__ float2 md2[NPAIRT * NTILE];     // 64 KiB, [k*512 + tile]
  __shared__ unsigned short oid[N_PTS];      // 32 KiB, [sorted pos] -> orig
  __shared__ int hist[NCELL], base_[NCELL], cnt[NCELL];
  __shared__ int scanA[NCELL], scanB[NCELL];
  __shared__ float bb6[6];
  __shared__ float wred[8][6];
  __shared__ unsigned long long skey[2][8];
  __shared__ float swx[2][8], swy[2][8], swz[2][8];

  // ---- setup: batch bbox (strided, coalesced) ----
  hist[t] = 0; cnt[t] = 0;
  float mnx = 1e30f, mny = 1e30f, mnz = 1e30f;
  float mxx = -1e30f, mxy = -1e30f, mxz = -1e30f;
  for (int i = 0; i < 32; ++i) {
    const int idx = i * FPS_THREADS + t;
    const float x = xyz[idx * 3 + 0];
    const float y = xyz[idx * 3 + 1];
    const float z = xyz[idx * 3 + 2];
    mnx = fminf(mnx, x); mxx = fmaxf(mxx, x);
    mny = fminf(mny, y); mxy = fmaxf(mxy, y);
    mnz = fminf(mnz, z); mxz = fmaxf(mxz, z);
  }
#pragma unroll
  for (int off = 32; off > 0; off >>= 1) {
    mnx = fminf(mnx, __shfl_xor(mnx, off)); mxx = fmaxf(mxx, __shfl_xor(mxx, off));
    mny = fminf(mny, __shfl_xor(mny, off)); mxy = fmaxf(mxy, __shfl_xor(mxy, off));
    mnz = fminf(mnz, __shfl_xor(mnz, off)); mxz = fmaxf(mxz, __shfl_xor(mxz, off));
  }
  if (lane == 0) {
    wred[wid][0] = mnx; wred[wid][1] = mny; wred[wid][2] = mnz;
    wred[wid][3] = mxx; wred[wid][4] = mxy; wred[wid][5] = mxz;
  }
  __syncthreads();
  if (t == 0) {
    float a0 = wred[0][0], a1 = wred[0][1], a2 = wred[0][2];
    float a3 = wred[0][3], a4 = wred[0][4], a5 = wred[0][5];
    for (int j = 1; j < 8; ++j) {
      a0 = fminf(a0, wred[j][0]); a1 = fminf(a1, wred[j][1]);
      a2 = fminf(a2, wred[j][2]); a3 = fmaxf(a3, wred[j][3]);
      a4 = fmaxf(a4, wred[j][4]); a5 = fmaxf(a5, wred[j][5]);
    }
    bb6[0] = a0; bb6[1] = a1; bb6[2] = a2;
    bb6[3] = 8.0f / fmaxf(a3 - a0, 1e-30f);
    bb6[4] = 8.0f / fmaxf(a4 - a1, 1e-30f);
    bb6[5] = 8.0f / fmaxf(a5 - a2, 1e-30f);
  }
  __syncthreads();
  const float c_mnx = bb6[0], c_mny = bb6[1], c_mnz = bb6[2];
  const float c_sx = bb6[3], c_sy = bb6[4], c_sz = bb6[5];

  // ---- setup: histogram ----
  for (int i = 0; i < 32; ++i) {
    const int idx = i * FPS_THREADS + t;
    const int cx = cell_coord(xyz[idx * 3 + 0], c_mnx, c_sx);
    const int cy = cell_coord(xyz[idx * 3 + 1], c_mny, c_sy);
    const int cz = cell_coord(xyz[idx * 3 + 2], c_mnz, c_sz);
    atomicAdd(&hist[(cx << 6) | (cy << 3) | cz], 1);
  }
  __syncthreads();
  // ---- setup: inclusive scan (Hillis-Steele ping-pong, r13-proven) ----
  scanA[t] = hist[t];
  __syncthreads();
#pragma unroll
  for (int step = 0; step < 9; ++step) {
    const int off = 1 << step;
    int* src = (step & 1) ? scanB : scanA;
    int* dst = (step & 1) ? scanA : scanB;
    const int v = src[t] + (t >= off ? src[t - off] : 0);
    dst[t] = v;
    __syncthreads();
  }
  base_[t] = scanB[t] - hist[t];
  __syncthreads();
  // ---- setup: scatter into ws (pair-transposed SoA) + oid ----
  for (int i = 0; i < 32; ++i) {
    const int idx = i * FPS_THREADS + t;
    const float x = xyz[idx * 3 + 0];
    const float y = xyz[idx * 3 + 1];
    const float z = xyz[idx * 3 + 2];
    const int cx = cell_coord(x, c_mnx, c_sx);
    const int cy = cell_coord(y, c_mny, c_sy);
    const int cz = cell_coord(z, c_mnz, c_sz);
    const int c = (cx << 6) | (cy << 3) | cz;
    const int pos = base_[c] + atomicAdd(&cnt[c], 1);
    const int tile = pos >> 5, w = pos & 31, k = w >> 1, comp = w & 1;
    wsx[(k * NTILE + tile) * 2 + comp] = x;
    wsy[(k * NTILE + tile) * 2 + comp] = y;
    wsz[(k * NTILE + tile) * 2 + comp] = z;
    oid[pos] = (unsigned short)idx;
  }
  __threadfence_block();
  __syncthreads();

  // ---- setup: per-tile bbox + packed inv-orig + md init ----
  const float2* wx2 = (const float2*)wsx;
  const float2* wy2 = (const float2*)wsy;
  const float2* wz2 = (const float2*)wsz;
  float bxl = 1e30f, byl = 1e30f, bzl = 1e30f;
  float bxh = -1e30f, byh = -1e30f, bzh = -1e30f;
  unsigned OP[NPAIRT];
#pragma unroll
  for (int k = 0; k < NPAIRT; ++k) {
    const float2 X = wx2[k * NTILE + t];
    const float2 Y = wy2[k * NTILE + t];
    const float2 Z = wz2[k * NTILE + t];
    bxl = fminf(bxl, fminf(X.x, X.y)); bxh = fmaxf(bxh, fmaxf(X.x, X.y));
    byl = fminf(byl, fminf(Y.x, Y.y)); byh = fmaxf(byh, fmaxf(Y.x, Y.y));
    bzl = fminf(bzl, fminf(Z.x, Z.y)); bzh = fmaxf(bzh, fmaxf(Z.x, Z.y));
    const unsigned o0 = oid[t * 32 + 2 * k];
    const unsigned o1 = oid[t * 32 + 2 * k + 1];
    OP[k] = ((16383u - o0) << 16) | (16383u - o1);
    md2[k * NTILE + t] = make_float2(1e10f, 1e10f);
  }
  asm("" : "+v"(bxl), "+v"(bxh), "+v"(byl), "+v"(byh), "+v"(bzl), "+v"(bzh));
#pragma unroll
  for (int k = 0; k < NPAIRT; ++k) asm("" : "+v"(OP[k]));
  unsigned long long tkey = (unsigned long long)__float_as_uint(1e10f) << 32;

  float px = xyz[0], py = xyz[1], pz = xyz[2];
  if (t == 0) {
    center[((size_t)b * N_GROUP) * 3 + 0] = px;
    center[((size_t)b * N_GROUP) * 3 + 1] = py;
    center[((size_t)b * N_GROUP) * 3 + 2] = pz;
  }
  __syncthreads();

  // ---- serial FPS loop: 1 barrier/iter ----
  for (int it = 1; it < N_GROUP; ++it) {
    const int p = it & 1;
    const float U = __uint_as_float((unsigned)(tkey >> 32));
    const float ddx = fmaxf(fmaxf(bxl - px, px - bxh), 0.0f);
    const float ddy = fmaxf(fmaxf(byl - py, py - byh), 0.0f);
    const float ddz = fmaxf(fmaxf(bzl - pz, pz - bzh), 0.0f);
    const float pd = ((ddx * ddx) + (ddy * ddy)) + (ddz * ddz);
    // conservative skip: margin 1.001 >> accumulated f32 rounding (r13-proven)
    if (pd < U * 1.001f) {
      const float2 npx2 = make_float2(-px, -px);
      const float2 npy2 = make_float2(-py, -py);
      const float2 npz2 = make_float2(-pz, -pz);
      unsigned long long nk = 0;
#pragma unroll
      for (int k = 0; k < NPAIRT; ++k) {
        const float2 X = wx2[k * NTILE + t];
        const float2 Y = wy2[k * NTILE + t];
        const float2 Z = wz2[k * NTILE + t];
        float2 M = md2[k * NTILE + t];
        const float2 dX = pk_add(X, npx2);   // x + (-px) == x - px
        const float2 dY = pk_add(Y, npy2);
        const float2 dZ = pk_add(Z, npz2);
        const float2 s2 = pk_add(pk_add(pk_sq(dX), pk_sq(dY)), pk_sq(dZ));
        M.x = fminf(M.x, s2.x);
        M.y = fminf(M.y, s2.y);
        md2[k * NTILE + t] = M;
        const unsigned long long k0 =
            ((unsigned long long)__float_as_uint(M.x) << 32) |
            ((unsigned long long)(OP[k] >> 16) << 14) |
            (unsigned)(t * 32 + 2 * k);
        const unsigned long long k1 =
            ((unsigned long long)__float_as_uint(M.y) << 32) |
            ((unsigned long long)(OP[k] & 0xffffu) << 14) |
            (unsigned)(t * 32 + 2 * k + 1);
        nk = maxu64(nk, maxu64(k0, k1));
      }
      tkey = nk;
    }
    // wave butterfly: max key (value, then lowest orig index)
    unsigned long long w = tkey;
#pragma unroll
    for (int off = 32; off > 0; off >>= 1) w = maxu64(w, shfl_xor_u64(w, off));
    if (lane == 0) {
      const int pos = (int)(w & 0x3fffull);
      const int tl = pos >> 5, ww = pos & 31, kk = ww >> 1, cc = ww & 1;
      skey[p][wid] = w;
      // wave-winner coords: bit-copies, loads hidden under the barrier
      swx[p][wid] = wsx[(kk * NTILE + tl) * 2 + cc];
      swy[p][wid] = wsy[(kk * NTILE + tl) * 2 + cc];
      swz[p][wid] = wsz[(kk * NTILE + tl) * 2 + cc];
    }
    __syncthreads();
    unsigned long long bk = skey[p][0];
    int bj = 0;
#pragma unroll
    for (int j = 1; j < 8; ++j) {
      const unsigned long long kj = skey[p][j];
      if (kj > bk) { bk = kj; bj = j; }
    }
    px = swx[p][bj]; py = swy[p][bj]; pz = swz[p][bj];
    if (t == 0) {
      center[((size_t)b * N_GROUP + it) * 3 + 0] = px;
      center[((size_t)b * N_GROUP + it) * 3 + 1] = py;
      center[((size_t)b * N_GROUP + it) * 3 + 2] = pz;
    }
    // single barrier/iter: double-buffered slots fence reuse at it+2.
  }
}

// ---------------------------------------------------------------------------
// kNN: one wave per center; lanes 0..15 hold the sorted top-16.
// d2 = (cc - 2*dot) + xx; cc/xx separate ops; dot = FMA chain (einsum).
// (unchanged from the bit-exact round-4 version)
// ---------------------------------------------------------------------------
__global__ __launch_bounds__(KNN_THREADS) void knn_kernel(
    const float* __restrict__ pcd, const float* __restrict__ center,
    float* __restrict__ nbr) {
#pragma clang fp contract(off)
  const int lane = threadIdx.x & 63;
  const int gw = blockIdx.x * KNN_WAVES + (threadIdx.x >> 6);  // center id
  const int b = gw >> 11;                                      // G = 2048
  const float* xyz = pcd + (size_t)b * N_PTS * 3;

  const float c0 = center[(size_t)gw * 3 + 0];
  const float c1 = center[(size_t)gw * 3 + 1];
  const float c2 = center[(size_t)gw * 3 + 2];
  const float cc = (fmul_sep(c0, c0) + fmul_sep(c1, c1)) + fmul_sep(c2, c2);

  float lval = INFINITY;  // lanes 0..15: sorted list values (ascending)
  int lidx = 0;
  float worst = INFINITY; // 16th-smallest so far, wave-uniform

  for (int ch = 0; ch < N_PTS / 64; ++ch) {
    const int n = ch * 64 + lane;
    const float xp = xyz[n * 3 + 0];
    const float yp = xyz[n * 3 + 1];
    const float zp = xyz[n * 3 + 2];
    const float xx = (fmul_sep(xp, xp) + fmul_sep(yp, yp)) + fmul_sep(zp, zp);
    // numpy einsum: acc=0; acc=fma(c0,x,acc); acc=fma(c1,y,acc); acc=fma(c2,z,acc)
    const float dot = fmaf(c2, zp, fmaf(c1, yp, c0 * xp));
    const float d2 = (cc - fmul_sep(2.0f, dot)) + xx;

    unsigned long long m = __ballot(d2 < worst);
    while (m) {
      const int srcl = __ffsll((unsigned long long)m) - 1;  // ascending index
      m &= (m - 1);
      const float nv = __shfl(d2, srcl);
      if (nv < worst) {  // wave-uniform decision
        const int ni = ch * 64 + srcl;
        const int rank = __popcll(__ballot(lane < GROUP_SIZE && lval <= nv));
        const float shv = __shfl_up(lval, 1);
        const int   shi = __shfl_up(lidx, 1);
        if (lane < GROUP_SIZE) {
          if (lane == rank)      { lval = nv;  lidx = ni;  }
          else if (lane > rank)  { lval = shv; lidx = shi; }
        }
        worst = __shfl(lval, 15);
      }
    }
  }

  if (lane < GROUP_SIZE) {
    const float ox = xyz[lidx * 3 + 0] - c0;
    const float oy = xyz[lidx * 3 + 1] - c1;
    const float oz = xyz[lidx * 3 + 2] - c2;
    const size_t o = ((size_t)gw * GROUP_SIZE + lane) * 3;
    nbr[o + 0] = ox; nbr[o + 1] = oy; nbr[o + 2] = oz;
  }
}

extern "C" void kernel_launch(void* const* d_in, const int* in_sizes, int n_in,
                              void* d_out, int out_size, void* d_ws, size_t ws_size,
                              hipStream_t stream) {
  const float* pcd = (const float*)d_in[0];
  const int B = in_sizes[0] / (N_PTS * 3);  // = 4

  float* out = (float*)d_out;
  float* nbr = out;                                            // B*G*M*3
  float* center = out + (size_t)B * N_GROUP * GROUP_SIZE * 3;  // B*G*3

  fps_kernel<<<B, FPS_THREADS, 0, stream>>>(pcd, center, (float*)d_ws);
  knn_kernel<<<(B * N_GROUP) / KNN_WAVES, KNN_THREADS, 0, stream>>>(pcd, center, nbr);
}